// Round 3
// baseline (295.124 us; speedup 1.0000x reference)
//
#include <hip/hip_runtime.h>

// VQ nearest-embedding, fused split-fp16 MFMA.
// argmin_k ||x-e_k||^2 == argmin_k (0.5*||e_k||^2 - x.e_k).
// x = xh+xl, e = eh+el (fp16 RNE splits); 3 MFMA terms (hh, hl, lh).
// R6: hoisted emb conversion to pack_emb (B reuse x1024 makes this mandatory).
// R7: MT=64, grid 512 -> 2 blocks/CU; but duplicated B staging per block
//     doubled per-CU VALU+LDS work and cancelled the occupancy gain.
// R8: NO-LDS main loop. MFMA fragments are loaded DIRECTLY from global
//     (coalesced 256B rows; B from packed emb planes, A from x f32 with
//     in-loop split16). Zero __syncthreads in the hot loop -> no per-chunk
//     vmcnt-drain stall, zero bank conflicts, staging VALU gone. Duplicate
//     fragment reads (B x2 waves, A x4 waves) are L1/L2 hits.
//     pack_x dropped (A conversion in-loop is cheaper than a 268MB pass).
//     Fragment bits and accumulation order identical -> absmax 0.

typedef __attribute__((ext_vector_type(8))) _Float16 half8v;  // 8 fp16 = 4 VGPRs
typedef __attribute__((ext_vector_type(16))) float floatx16;  // 32x32 acc
typedef unsigned int uint;
typedef unsigned short ushort;

#define DD 256
#define KK 2048
#define SS 1024
#define NN 32768
#define MT 64       // latents per block
#define NTT 256     // codes per kt tile (8 tiles cover K=2048)
#define LDA 24      // LDS row stride (fallback kernel only)
#define MFMA_F16 __builtin_amdgcn_mfma_f32_32x32x16_f16

#define XSLAB  262144   // (fallback template refs)
#define XPLANE 131072
#define EPLANE 262144   // uints per packed-emb plane: 128 d2 * 2048 k

union HU { _Float16 f; ushort u; };
union FragU { uint u[4]; half8v v; };

__device__ __forceinline__ void split16(float v, ushort& h, ushort& l) {
    HU a, b;
    a.f = (_Float16)v;                       // RNE
    b.f = (_Float16)(v - (float)a.f);
    h = a.u; l = b.u;
}

__global__ __launch_bounds__(256) void hn_kernel(const float* __restrict__ emb,
                                                 float* __restrict__ hn) {
    int k = blockIdx.x * 256 + threadIdx.x;
    float a = 0.f;
#pragma unroll 32
    for (int d = 0; d < DD; ++d) { float e = emb[d * KK + k]; a += e * e; }
    hn[k] = 0.5f * a;
}

// emb (d,k) f32 -> eh2/el2 (d2,k) uints: h(2*d2)|h(2*d2+1)<<16 etc.
__global__ __launch_bounds__(256) void pack_emb(const float* __restrict__ emb,
                                                uint* __restrict__ epk) {
    int idx = blockIdx.x * 256 + threadIdx.x;     // 262144 = 128 d2 * 2048 k
    int k = idx & (KK - 1);
    int d2 = idx >> 11;
    float a = emb[(size_t)(2 * d2) * KK + k];
    float b = emb[(size_t)(2 * d2 + 1) * KK + k];
    ushort h0, l0, h1, l1;
    split16(a, h0, l0);
    split16(b, h1, l1);
    epk[idx] = (uint)h0 | ((uint)h1 << 16);
    epk[EPLANE + idx] = (uint)l0 | ((uint)l1 << 16);
}

// ---------------- R8 main kernel: no LDS in hot loop ----------------
__global__ __launch_bounds__(512, 4) void vq_direct(
        const float* __restrict__ x, const uint* __restrict__ epk,
        const float* __restrict__ hn, const float* __restrict__ emb,
        float* __restrict__ out) {
    __shared__ float sv[4][MT];
    __shared__ int   sc[4][MT];
    __shared__ int   bc[MT];

    const int tid = threadIdx.x;
    const int lane = tid & 63;
    const int wid = tid >> 6;          // 8 waves: 2(m) x 4(n)
    const int colk = lane & 31;
    const int half = lane >> 5;
    const int wm = __builtin_amdgcn_readfirstlane((wid & 1) * 32);
    const int wn = __builtin_amdgcn_readfirstlane((wid >> 1) * 64);

    const int base_n = blockIdx.x * MT;
    const int bq = base_n >> 10;          // batch (SS = 1024)
    const int sb = base_n & (SS - 1);     // spatial base

    // A: lane (colk,half) covers latent s = sb+wm+colk, d = dt + half*8 + j
    const float* xA = x + ((size_t)bq * DD + half * 8) * SS + (sb + wm + colk);
    // B: per-lane constant offsets into packed emb planes
    const int oB0 = half * 4 * KK + wn + colk;
    const int oB1 = oB0 + 32;

    floatx16 acc[2];
#pragma unroll
    for (int j = 0; j < 2; ++j) acc[j] = (floatx16)(0.0f);

    float bestv[16];
    int bestc[16];
#pragma unroll
    for (int r = 0; r < 16; ++r) { bestv[r] = 3.4e38f; bestc[r] = 0; }

    float fa[8], pa[8];            // raw A f32 (cur / prefetch)
    uint rbh[2][4], rbl[2][4];     // raw B uints (cur)
    uint pbh[2][4], pbl[2][4];     // raw B uints (prefetch)

    // ---- load chunk 0 (kt=0, dt=0) ----
#pragma unroll
    for (int j = 0; j < 8; ++j) fa[j] = xA[(size_t)j * SS];
    {
        const uint* uB = epk;      // dh=0, kt=0
#pragma unroll
        for (int j = 0; j < 4; ++j) {
            rbh[0][j] = uB[oB0 + (size_t)j * KK];
            rbh[1][j] = uB[oB1 + (size_t)j * KK];
            rbl[0][j] = uB[(size_t)EPLANE + oB0 + (size_t)j * KK];
            rbl[1][j] = uB[(size_t)EPLANE + oB1 + (size_t)j * KK];
        }
    }

#pragma unroll 2
    for (int c = 0; c < 128; ++c) {      // 8 kt x 16 dt chunks of K-depth 16
        // ---- issue next chunk's loads (latency hides under this chunk) ----
        if (c < 127) {
            const int c1 = c + 1;
            const int kt1 = c1 >> 4;
            const int dh1 = (c1 & 15) * 8;          // dt/2, uniform
            const float* pxa = xA + (size_t)(dh1 * 2) * SS;
#pragma unroll
            for (int j = 0; j < 8; ++j) pa[j] = pxa[(size_t)j * SS];
            const uint* uB = epk + (size_t)dh1 * KK + kt1 * NTT;
#pragma unroll
            for (int j = 0; j < 4; ++j) {
                pbh[0][j] = uB[oB0 + (size_t)j * KK];
                pbh[1][j] = uB[oB1 + (size_t)j * KK];
                pbl[0][j] = uB[(size_t)EPLANE + oB0 + (size_t)j * KK];
                pbl[1][j] = uB[(size_t)EPLANE + oB1 + (size_t)j * KK];
            }
        }
        // ---- convert current A, assemble fragments, 6 MFMA ----
        ushort h[8], l[8];
#pragma unroll
        for (int j = 0; j < 8; ++j) split16(fa[j], h[j], l[j]);
        FragU ah, al, b0h, b1h, b0l, b1l;
#pragma unroll
        for (int j = 0; j < 4; ++j) {
            ah.u[j] = (uint)h[2 * j] | ((uint)h[2 * j + 1] << 16);
            al.u[j] = (uint)l[2 * j] | ((uint)l[2 * j + 1] << 16);
            b0h.u[j] = rbh[0][j];
            b1h.u[j] = rbh[1][j];
            b0l.u[j] = rbl[0][j];
            b1l.u[j] = rbl[1][j];
        }
        acc[0] = MFMA_F16(ah.v, b0h.v, acc[0], 0, 0, 0);
        acc[0] = MFMA_F16(ah.v, b0l.v, acc[0], 0, 0, 0);
        acc[0] = MFMA_F16(al.v, b0h.v, acc[0], 0, 0, 0);

        acc[1] = MFMA_F16(ah.v, b1h.v, acc[1], 0, 0, 0);
        acc[1] = MFMA_F16(ah.v, b1l.v, acc[1], 0, 0, 0);
        acc[1] = MFMA_F16(al.v, b1h.v, acc[1], 0, 0, 0);

        // ---- per-kt epilogue: scores -> running per-lane argmin, reset acc ----
        if ((c & 15) == 15) {
            const int kt = c >> 4;
            const int cd0 = kt * NTT + wn + colk;
            const int cd1 = cd0 + 32;
            const float h0 = hn[cd0];
            const float h1 = hn[cd1];
#pragma unroll
            for (int r = 0; r < 16; ++r) {
                float s0 = h0 - acc[0][r];
                float s1 = h1 - acc[1][r];
                float v = s0; int cd = cd0;
                if (s1 < s0) { v = s1; cd = cd1; }   // strict <: smaller code wins ties
                if (v < bestv[r]) { bestv[r] = v; bestc[r] = cd; }
                acc[0][r] = 0.f;
                acc[1][r] = 0.f;
            }
        }
        // ---- rotate prefetched -> current (renamed away under unroll 2) ----
        if (c < 127) {
#pragma unroll
            for (int j = 0; j < 8; ++j) fa[j] = pa[j];
#pragma unroll
            for (int j = 0; j < 4; ++j) {
                rbh[0][j] = pbh[0][j];
                rbh[1][j] = pbh[1][j];
                rbl[0][j] = pbl[0][j];
                rbl[1][j] = pbl[1][j];
            }
        }
    }

    // ---- cross-lane argmin: butterfly over the 32 colk lanes ----
#pragma unroll
    for (int r = 0; r < 16; ++r) {
        float v = bestv[r];
        int cd = bestc[r];
#pragma unroll
        for (int mk = 1; mk < 32; mk <<= 1) {
            float ov = __shfl_xor(v, mk);
            int oc = __shfl_xor(cd, mk);
            if (ov < v || (ov == v && oc < cd)) { v = ov; cd = oc; }
        }
        if (colk == 0) {
            const int row = (r & 3) + 8 * (r >> 2) + 4 * half;  // verified C/D map
            sv[wid >> 1][wm + row] = v;
            sc[wid >> 1][wm + row] = cd;
        }
    }
    __syncthreads();
    // ---- combine the 4 n-wave groups ----
    if (tid < MT) {
        float v = sv[0][tid]; int cd = sc[0][tid];
#pragma unroll
        for (int g = 1; g < 4; ++g) {
            float ov = sv[g][tid]; int oc = sc[g][tid];
            if (ov < v || (ov == v && oc < cd)) { v = ov; cd = oc; }
        }
        bc[tid] = cd;
    }
    __syncthreads();
    // ---- fused gather: out[(bq*DD+d)*SS + sb + m] = emb[d*KK + bc[m]] ----
    {
        const int mq = tid & 15;     // float4 group along m (64 cols = 16 groups)
        const int dg = tid >> 4;     // 0..31, 8 d's each
        const int k0 = bc[mq * 4 + 0];
        const int k1 = bc[mq * 4 + 1];
        const int k2 = bc[mq * 4 + 2];
        const int k3 = bc[mq * 4 + 3];
#pragma unroll 4
        for (int dd = 0; dd < 8; ++dd) {
            const int d = dg * 8 + dd;
            const float* er = emb + (size_t)d * KK;
            float4 o = make_float4(er[k0], er[k1], er[k2], er[k3]);
            reinterpret_cast<float4*>(&out[((size_t)bq * DD + d) * SS + sb])[mq] = o;
        }
    }
}

// ---------------- fallback (ws too small): R7 LDS kernel, convert-in-loop ----
template <bool PRE>
__global__ __launch_bounds__(512, 4) void vq_fused(
        const float* __restrict__ x, const float* __restrict__ emb,
        const float* __restrict__ hn, const uint* __restrict__ epk,
        float* out) {
    __shared__ ushort Ah[2][MT * LDA], Al[2][MT * LDA];
    __shared__ ushort Bh[2][NTT * LDA], Bl[2][NTT * LDA];
    __shared__ float sv[4][MT];
    __shared__ int   sc[4][MT];
    __shared__ int   bc[MT];

    const int tid = threadIdx.x;
    const int lane = tid & 63;
    const int wid = tid >> 6;
    const int colk = lane & 31;
    const int half = lane >> 5;
    const int wm = (wid & 1) * 32;
    const int wn = (wid >> 1) * 64;

    const int base_n = blockIdx.x * MT;
    const int bq = base_n >> 10;
    const int sb = base_n & (SS - 1);

    const int lat_a = tid & 63;
    const int dqa2 = tid >> 6;
    const int cod_b = tid & 255;
    const int dqb = (tid >> 8) * 8;

    const float* xb = x + ((size_t)bq * DD + 2 * dqa2) * SS + sb + lat_a;

    floatx16 acc[2];
#pragma unroll
    for (int j = 0; j < 2; ++j) acc[j] = (floatx16)(0.0f);

    float bestv[16];
    int bestc[16];
#pragma unroll
    for (int r = 0; r < 16; ++r) { bestv[r] = 3.4e38f; bestc[r] = 0; }

    float fa[2], fb[8];
    fa[0] = xb[0];
    fa[1] = xb[SS];
    {
        const float* p = emb + (size_t)dqb * KK + cod_b;
#pragma unroll
        for (int i = 0; i < 8; ++i) fb[i] = p[(size_t)i * KK];
    }
    {
        ushort h[8], l[8];
        split16(fa[0], h[0], l[0]);
        split16(fa[1], h[1], l[1]);
        *reinterpret_cast<uint*>(&Ah[0][lat_a * LDA + dqa2 * 2]) =
            (uint)h[0] | ((uint)h[1] << 16);
        *reinterpret_cast<uint*>(&Al[0][lat_a * LDA + dqa2 * 2]) =
            (uint)l[0] | ((uint)l[1] << 16);
#pragma unroll
        for (int i = 0; i < 8; ++i) split16(fb[i], h[i], l[i]);
        uint4 t;
        t.x = (uint)h[0] | ((uint)h[1] << 16);
        t.y = (uint)h[2] | ((uint)h[3] << 16);
        t.z = (uint)h[4] | ((uint)h[5] << 16);
        t.w = (uint)h[6] | ((uint)h[7] << 16);
        *reinterpret_cast<uint4*>(&Bh[0][cod_b * LDA + dqb]) = t;
        t.x = (uint)l[0] | ((uint)l[1] << 16);
        t.y = (uint)l[2] | ((uint)l[3] << 16);
        t.z = (uint)l[4] | ((uint)l[5] << 16);
        t.w = (uint)l[6] | ((uint)l[7] << 16);
        *reinterpret_cast<uint4*>(&Bl[0][cod_b * LDA + dqb]) = t;
    }
    __syncthreads();

    for (int c = 0; c < 128; ++c) {
        const int cur = c & 1, nxt = cur ^ 1;
        if (c < 127) {
            const int c1 = c + 1;
            const int kt1 = c1 >> 4;
            const int dt1 = (c1 & 15) * 16;
            fa[0] = xb[(size_t)dt1 * SS];
            fa[1] = xb[(size_t)dt1 * SS + SS];
            const float* p = emb + (size_t)(dt1 + dqb) * KK + kt1 * NTT + cod_b;
#pragma unroll
            for (int i = 0; i < 8; ++i) fb[i] = p[(size_t)i * KK];
        }
        const int fo = colk * LDA + half * 8;
        half8v ah = *reinterpret_cast<const half8v*>(&Ah[cur][fo + wm * LDA]);
        half8v al = *reinterpret_cast<const half8v*>(&Al[cur][fo + wm * LDA]);
        half8v bh0 = *reinterpret_cast<const half8v*>(&Bh[cur][fo + wn * LDA]);
        half8v bh1 = *reinterpret_cast<const half8v*>(&Bh[cur][fo + (wn + 32) * LDA]);
        half8v bl0 = *reinterpret_cast<const half8v*>(&Bl[cur][fo + wn * LDA]);
        half8v bl1 = *reinterpret_cast<const half8v*>(&Bl[cur][fo + (wn + 32) * LDA]);

        acc[0] = MFMA_F16(ah, bh0, acc[0], 0, 0, 0);
        acc[0] = MFMA_F16(ah, bl0, acc[0], 0, 0, 0);
        acc[0] = MFMA_F16(al, bh0, acc[0], 0, 0, 0);

        acc[1] = MFMA_F16(ah, bh1, acc[1], 0, 0, 0);
        acc[1] = MFMA_F16(ah, bl1, acc[1], 0, 0, 0);
        acc[1] = MFMA_F16(al, bh1, acc[1], 0, 0, 0);

        if (c < 127) {
            ushort h[8], l[8];
            split16(fa[0], h[0], l[0]);
            split16(fa[1], h[1], l[1]);
            *reinterpret_cast<uint*>(&Ah[nxt][lat_a * LDA + dqa2 * 2]) =
                (uint)h[0] | ((uint)h[1] << 16);
            *reinterpret_cast<uint*>(&Al[nxt][lat_a * LDA + dqa2 * 2]) =
                (uint)l[0] | ((uint)l[1] << 16);
#pragma unroll
            for (int i = 0; i < 8; ++i) split16(fb[i], h[i], l[i]);
            uint4 t;
            t.x = (uint)h[0] | ((uint)h[1] << 16);
            t.y = (uint)h[2] | ((uint)h[3] << 16);
            t.z = (uint)h[4] | ((uint)h[5] << 16);
            t.w = (uint)h[6] | ((uint)h[7] << 16);
            *reinterpret_cast<uint4*>(&Bh[nxt][cod_b * LDA + dqb]) = t;
            t.x = (uint)l[0] | ((uint)l[1] << 16);
            t.y = (uint)l[2] | ((uint)l[3] << 16);
            t.z = (uint)l[4] | ((uint)l[5] << 16);
            t.w = (uint)l[6] | ((uint)l[7] << 16);
            *reinterpret_cast<uint4*>(&Bl[nxt][cod_b * LDA + dqb]) = t;
        }
        if ((c & 15) == 15) {
            const int kt = c >> 4;
            const int cd0 = kt * NTT + wn + colk;
            const int cd1 = cd0 + 32;
            const float h0 = hn[cd0];
            const float h1 = hn[cd1];
#pragma unroll
            for (int r = 0; r < 16; ++r) {
                float s0 = h0 - acc[0][r];
                float s1 = h1 - acc[1][r];
                float v = s0; int cd = cd0;
                if (s1 < s0) { v = s1; cd = cd1; }
                if (v < bestv[r]) { bestv[r] = v; bestc[r] = cd; }
                acc[0][r] = 0.f;
                acc[1][r] = 0.f;
            }
        }
        __syncthreads();
    }

#pragma unroll
    for (int r = 0; r < 16; ++r) {
        float v = bestv[r];
        int cd = bestc[r];
#pragma unroll
        for (int mk = 1; mk < 32; mk <<= 1) {
            float ov = __shfl_xor(v, mk);
            int oc = __shfl_xor(cd, mk);
            if (ov < v || (ov == v && oc < cd)) { v = ov; cd = oc; }
        }
        if (colk == 0) {
            const int row = (r & 3) + 8 * (r >> 2) + 4 * half;
            sv[wid >> 1][wm + row] = v;
            sc[wid >> 1][wm + row] = cd;
        }
    }
    __syncthreads();
    if (tid < MT) {
        float v = sv[0][tid]; int cd = sc[0][tid];
#pragma unroll
        for (int g = 1; g < 4; ++g) {
            float ov = sv[g][tid]; int oc = sc[g][tid];
            if (ov < v || (ov == v && oc < cd)) { v = ov; cd = oc; }
        }
        bc[tid] = cd;
    }
    __syncthreads();
    {
        const int mq = tid & 15;
        const int dg = tid >> 4;
        const int k0 = bc[mq * 4 + 0];
        const int k1 = bc[mq * 4 + 1];
        const int k2 = bc[mq * 4 + 2];
        const int k3 = bc[mq * 4 + 3];
#pragma unroll 4
        for (int dd = 0; dd < 8; ++dd) {
            const int d = dg * 8 + dd;
            const float* er = emb + (size_t)d * KK;
            float4 o = make_float4(er[k0], er[k1], er[k2], er[k3]);
            reinterpret_cast<float4*>(&out[((size_t)bq * DD + d) * SS + sb])[mq] = o;
        }
    }
}

extern "C" void kernel_launch(void* const* d_in, const int* in_sizes, int n_in,
                              void* d_out, int out_size, void* d_ws, size_t ws_size,
                              hipStream_t stream) {
    const float* x = (const float*)d_in[0];     // (32,256,32,32)
    const float* emb = (const float*)d_in[1];   // (256,2048)
    float* out = (float*)d_out;
    float* hn = (float*)d_ws;                   // 2048 f32 = 8 KB (proven safe)
    uint* epk = (uint*)((char*)d_ws + KK * sizeof(float));  // 2 MB packed emb

    const size_t need = (size_t)KK * 4 + (size_t)2 * EPLANE * 4;  // 2.01 MB

    hipLaunchKernelGGL(hn_kernel, dim3(KK / 256), dim3(256), 0, stream, emb, hn);
    if (ws_size >= need) {
        hipLaunchKernelGGL(pack_emb, dim3(EPLANE / 256), dim3(256), 0, stream,
                           emb, epk);
        hipLaunchKernelGGL(vq_direct, dim3(NN / MT), dim3(512), 0, stream,
                           x, epk, hn, emb, out);
    } else {
        hipLaunchKernelGGL((vq_fused<false>), dim3(NN / MT), dim3(512), 0, stream,
                           x, emb, hn, epk, out);
    }
}

// Round 4
// 235.857 us; speedup vs baseline: 1.2513x; 1.2513x over previous
//
#include <hip/hip_runtime.h>

// VQ nearest-embedding, fused split-fp16 MFMA, double-buffered LDS.
// argmin_k ||x-e_k||^2 == argmin_k (0.5*||e_k||^2 - x.e_k).
// x = xh+xl, e = eh+el (fp16 RNE splits); 3 MFMA terms (hh, hl, lh).
// R6: pack_emb hoists B conversion (reuse x1024). 183us @ 2 waves/SIMD.
// R7: 2 blocks/CU duplicated B staging -> regression (staging VALU/LDS x2).
// R8: no-LDS direct fragments -> VGPR spill catastrophe (WRITE 107MB).
// R9: ONE 1024-thread block per CU. MT=128, 16 waves (4m x 4n):
//     - B staged once per CU (R6's per-CU cost), but 4 waves/SIMD of
//       latency cover (R7's occupancy) -> the chunk chain
//       load->vmcnt->ds_write->barrier->ds_read->MFMA is TLP-hidden.
//     - A converted in-loop (2 split16/thread/chunk), pack_x dropped.
//     - LDS layout, fragment formulas, epilogue, tie-breaks identical to
//       the verified R6/R7 kernels -> absmax 0.
//     - hn_kernel: 64 blocks (8 partial-d sums + LDS reduce).

typedef __attribute__((ext_vector_type(8))) _Float16 half8v;  // 8 fp16 = 4 VGPRs
typedef __attribute__((ext_vector_type(16))) float floatx16;  // 32x32 acc
typedef unsigned int uint;
typedef unsigned short ushort;

#define DD 256
#define KK 2048
#define SS 1024
#define NN 32768
#define MT 128      // latents per block
#define NTT 256     // codes per kt tile (8 tiles cover K=2048)
#define LDA 24      // LDS row stride in fp16 elems (48 B: 16B-aligned, banks spread)
#define MFMA_F16 __builtin_amdgcn_mfma_f32_32x32x16_f16

#define EPLANE 262144   // uints per packed-emb plane: 128 d2 * 2048 k

union HU { _Float16 f; ushort u; };

__device__ __forceinline__ void split16(float v, ushort& h, ushort& l) {
    HU a, b;
    a.f = (_Float16)v;                       // RNE
    b.f = (_Float16)(v - (float)a.f);
    h = a.u; l = b.u;
}

// 64 blocks: block b covers codes [b*32, b*32+32); 8 threads/code sum 32 d's.
__global__ __launch_bounds__(256) void hn_kernel(const float* __restrict__ emb,
                                                 float* __restrict__ hn) {
    __shared__ float red[256];
    const int tid = threadIdx.x;
    const int k = blockIdx.x * 32 + (tid & 31);
    const int j = tid >> 5;              // 0..7: d-chunk
    float a = 0.f;
#pragma unroll
    for (int i = 0; i < 32; ++i) {
        float e = emb[(size_t)(j * 32 + i) * KK + k];
        a += e * e;
    }
    red[tid] = a;
    __syncthreads();
    if (j == 0) {
        float s = a;
#pragma unroll
        for (int g = 1; g < 8; ++g) s += red[g * 32 + (tid & 31)];
        hn[k] = 0.5f * s;
    }
}

// emb (d,k) f32 -> eh2/el2 (d2,k) uints: h(2*d2)|h(2*d2+1)<<16 etc.
__global__ __launch_bounds__(256) void pack_emb(const float* __restrict__ emb,
                                                uint* __restrict__ epk) {
    int idx = blockIdx.x * 256 + threadIdx.x;     // 262144 = 128 d2 * 2048 k
    int k = idx & (KK - 1);
    int d2 = idx >> 11;
    float a = emb[(size_t)(2 * d2) * KK + k];
    float b = emb[(size_t)(2 * d2 + 1) * KK + k];
    ushort h0, l0, h1, l1;
    split16(a, h0, l0);
    split16(b, h1, l1);
    epk[idx] = (uint)h0 | ((uint)h1 << 16);
    epk[EPLANE + idx] = (uint)l0 | ((uint)l1 << 16);
}

// PRE: B from packed epk planes. !PRE: B from emb f32 + in-loop split.
template <bool PRE>
__global__ __launch_bounds__(1024, 4) void vq_fused(
        const float* __restrict__ x, const float* __restrict__ emb,
        const float* __restrict__ hn, const uint* __restrict__ epk,
        float* __restrict__ out) {
    __shared__ ushort Ah[2][MT * LDA], Al[2][MT * LDA];     // 6 KB each plane/buf
    __shared__ ushort Bh[2][NTT * LDA], Bl[2][NTT * LDA];   // 12 KB each plane/buf
    __shared__ float sv[4][MT];
    __shared__ int   sc[4][MT];
    __shared__ int   bc[MT];

    const int tid = threadIdx.x;
    const int lane = tid & 63;
    const int wid = tid >> 6;          // 16 waves: 4(m) x 4(n)
    const int colk = lane & 31;
    const int half = lane >> 5;
    const int wm = (wid & 3) * 32;     // 4 m-tiles of 32 cover MT=128
    const int wn = (wid >> 2) * 64;    // 4 n-groups of 64 (2 tiles each)

    const int base_n = blockIdx.x * MT;
    const int bq = base_n >> 10;          // batch (SS = 1024)
    const int sb = base_n & (SS - 1);     // spatial base

    // staging assignment (1024 threads)
    const int lat_a = tid & 127;          // A: one latent, 1 d2 (2 d's)
    const int d2a = tid >> 7;             // 0..7 d-pair within chunk
    const int cod_b = tid & 255;          // B: one code, 2 d2 (4 d's)
    const int qb = tid >> 8;              // 0..3

    // A global base: d = 2*d2a + {0,1} within chunk, latent sb+lat_a
    const float* xA = x + ((size_t)bq * DD + 2 * d2a) * SS + sb + lat_a;

    floatx16 acc[2];                      // 2 n-tiles (wn, wn+32)
#pragma unroll
    for (int j = 0; j < 2; ++j) acc[j] = (floatx16)(0.0f);

    float bestv[16];
    int bestc[16];
#pragma unroll
    for (int r = 0; r < 16; ++r) { bestv[r] = 3.4e38f; bestc[r] = 0; }

    float fa[2];
    uint ub[4];            // PRE: {h,h,l,l} raw uints
    float fb[4];           // !PRE: raw f32

    // ---- prefetch chunk 0 (kt=0, dt=0) ----
    fa[0] = xA[0];
    fa[1] = xA[SS];
    if constexpr (PRE) {
        const uint* uB = epk + (size_t)(2 * qb) * KK + cod_b;
        ub[0] = uB[0];
        ub[1] = uB[KK];
        ub[2] = uB[EPLANE];
        ub[3] = uB[EPLANE + KK];
    } else {
        const float* p = emb + (size_t)(4 * qb) * KK + cod_b;
#pragma unroll
        for (int i = 0; i < 4; ++i) fb[i] = p[(size_t)i * KK];
    }
    // ---- stage chunk 0 -> buffer 0 ----
    {
        ushort h0, l0, h1, l1;
        split16(fa[0], h0, l0);
        split16(fa[1], h1, l1);
        *reinterpret_cast<uint*>(&Ah[0][lat_a * LDA + 2 * d2a]) =
            (uint)h0 | ((uint)h1 << 16);
        *reinterpret_cast<uint*>(&Al[0][lat_a * LDA + 2 * d2a]) =
            (uint)l0 | ((uint)l1 << 16);
        uint2 wh, wl;
        if constexpr (PRE) {
            wh.x = ub[0]; wh.y = ub[1];
            wl.x = ub[2]; wl.y = ub[3];
        } else {
            ushort h[4], l[4];
#pragma unroll
            for (int i = 0; i < 4; ++i) split16(fb[i], h[i], l[i]);
            wh.x = (uint)h[0] | ((uint)h[1] << 16);
            wh.y = (uint)h[2] | ((uint)h[3] << 16);
            wl.x = (uint)l[0] | ((uint)l[1] << 16);
            wl.y = (uint)l[2] | ((uint)l[3] << 16);
        }
        *reinterpret_cast<uint2*>(&Bh[0][cod_b * LDA + 4 * qb]) = wh;
        *reinterpret_cast<uint2*>(&Bl[0][cod_b * LDA + 4 * qb]) = wl;
    }
    __syncthreads();

    for (int c = 0; c < 128; ++c) {          // 8 kt x 16 dt chunks of K-depth 16
        const int cur = c & 1, nxt = cur ^ 1;
        // ---- prefetch next chunk's globals (in flight during MFMA) ----
        if (c < 127) {
            const int c1 = c + 1;
            const int kt1 = c1 >> 4;
            const int dt1 = (c1 & 15) * 16;
            fa[0] = xA[(size_t)dt1 * SS];
            fa[1] = xA[(size_t)dt1 * SS + SS];
            if constexpr (PRE) {
                const uint* uB = epk + (size_t)(dt1 / 2 + 2 * qb) * KK
                                 + kt1 * NTT + cod_b;
                ub[0] = uB[0];
                ub[1] = uB[KK];
                ub[2] = uB[EPLANE];
                ub[3] = uB[EPLANE + KK];
            } else {
                const float* p = emb + (size_t)(dt1 + 4 * qb) * KK
                                 + kt1 * NTT + cod_b;
#pragma unroll
                for (int i = 0; i < 4; ++i) fb[i] = p[(size_t)i * KK];
            }
        }
        // ---- fragments from current buffer + 6 MFMA (3 terms x 1x2) ----
        const int fo = colk * LDA + half * 8;
        half8v ah = *reinterpret_cast<const half8v*>(&Ah[cur][fo + wm * LDA]);
        half8v al = *reinterpret_cast<const half8v*>(&Al[cur][fo + wm * LDA]);
        half8v bh0 = *reinterpret_cast<const half8v*>(&Bh[cur][fo + wn * LDA]);
        half8v bh1 = *reinterpret_cast<const half8v*>(&Bh[cur][fo + (wn + 32) * LDA]);
        half8v bl0 = *reinterpret_cast<const half8v*>(&Bl[cur][fo + wn * LDA]);
        half8v bl1 = *reinterpret_cast<const half8v*>(&Bl[cur][fo + (wn + 32) * LDA]);

        acc[0] = MFMA_F16(ah, bh0, acc[0], 0, 0, 0);
        acc[0] = MFMA_F16(ah, bl0, acc[0], 0, 0, 0);
        acc[0] = MFMA_F16(al, bh0, acc[0], 0, 0, 0);

        acc[1] = MFMA_F16(ah, bh1, acc[1], 0, 0, 0);
        acc[1] = MFMA_F16(ah, bl1, acc[1], 0, 0, 0);
        acc[1] = MFMA_F16(al, bh1, acc[1], 0, 0, 0);

        // ---- stage prefetched -> NEXT buffer (overlaps MFMA) ----
        if (c < 127) {
            ushort h0, l0, h1, l1;
            split16(fa[0], h0, l0);
            split16(fa[1], h1, l1);
            *reinterpret_cast<uint*>(&Ah[nxt][lat_a * LDA + 2 * d2a]) =
                (uint)h0 | ((uint)h1 << 16);
            *reinterpret_cast<uint*>(&Al[nxt][lat_a * LDA + 2 * d2a]) =
                (uint)l0 | ((uint)l1 << 16);
            uint2 wh, wl;
            if constexpr (PRE) {
                wh.x = ub[0]; wh.y = ub[1];
                wl.x = ub[2]; wl.y = ub[3];
            } else {
                ushort h[4], l[4];
#pragma unroll
                for (int i = 0; i < 4; ++i) split16(fb[i], h[i], l[i]);
                wh.x = (uint)h[0] | ((uint)h[1] << 16);
                wh.y = (uint)h[2] | ((uint)h[3] << 16);
                wl.x = (uint)l[0] | ((uint)l[1] << 16);
                wl.y = (uint)l[2] | ((uint)l[3] << 16);
            }
            *reinterpret_cast<uint2*>(&Bh[nxt][cod_b * LDA + 4 * qb]) = wh;
            *reinterpret_cast<uint2*>(&Bl[nxt][cod_b * LDA + 4 * qb]) = wl;
        }
        // ---- per-kt epilogue: scores -> running per-lane argmin, reset acc ----
        if ((c & 15) == 15) {
            const int kt = c >> 4;
            const int cd0 = kt * NTT + wn + colk;
            const int cd1 = cd0 + 32;
            const float h0 = hn[cd0];
            const float h1 = hn[cd1];
#pragma unroll
            for (int r = 0; r < 16; ++r) {
                float s0 = h0 - acc[0][r];
                float s1 = h1 - acc[1][r];
                float v = s0; int cd = cd0;
                if (s1 < s0) { v = s1; cd = cd1; }   // strict <: smaller code wins ties
                if (v < bestv[r]) { bestv[r] = v; bestc[r] = cd; }
                acc[0][r] = 0.f;
                acc[1][r] = 0.f;
            }
        }
        __syncthreads();   // single barrier per chunk (dbuf)
    }

    // ---- cross-lane argmin: butterfly over the 32 colk lanes ----
#pragma unroll
    for (int r = 0; r < 16; ++r) {
        float v = bestv[r];
        int cd = bestc[r];
#pragma unroll
        for (int mk = 1; mk < 32; mk <<= 1) {
            float ov = __shfl_xor(v, mk);
            int oc = __shfl_xor(cd, mk);
            if (ov < v || (ov == v && oc < cd)) { v = ov; cd = oc; }
        }
        if (colk == 0) {
            const int row = (r & 3) + 8 * (r >> 2) + 4 * half;  // verified C/D map
            sv[wid >> 2][wm + row] = v;
            sc[wid >> 2][wm + row] = cd;
        }
    }
    __syncthreads();
    // ---- combine the 4 n-wave groups ----
    if (tid < MT) {
        float v = sv[0][tid]; int cd = sc[0][tid];
#pragma unroll
        for (int g = 1; g < 4; ++g) {
            float ov = sv[g][tid]; int oc = sc[g][tid];
            if (ov < v || (ov == v && oc < cd)) { v = ov; cd = oc; }
        }
        bc[tid] = cd;
    }
    __syncthreads();
    // ---- fused gather: out[(bq*DD+d)*SS + sb + m] = emb[d*KK + bc[m]] ----
    {
        const int mq = tid & 31;     // float4 group along m (128 cols = 32 groups)
        const int dg = tid >> 5;     // 0..31, 8 d's each
        const int k0 = bc[mq * 4 + 0];
        const int k1 = bc[mq * 4 + 1];
        const int k2 = bc[mq * 4 + 2];
        const int k3 = bc[mq * 4 + 3];
#pragma unroll 4
        for (int dd = 0; dd < 8; ++dd) {
            const int d = dg * 8 + dd;
            const float* er = emb + (size_t)d * KK;
            float4 o = make_float4(er[k0], er[k1], er[k2], er[k3]);
            reinterpret_cast<float4*>(&out[((size_t)bq * DD + d) * SS + sb])[mq] = o;
        }
    }
}

extern "C" void kernel_launch(void* const* d_in, const int* in_sizes, int n_in,
                              void* d_out, int out_size, void* d_ws, size_t ws_size,
                              hipStream_t stream) {
    const float* x = (const float*)d_in[0];     // (32,256,32,32)
    const float* emb = (const float*)d_in[1];   // (256,2048)
    float* out = (float*)d_out;
    float* hn = (float*)d_ws;                   // 2048 f32 = 8 KB (proven safe)
    uint* epk = (uint*)((char*)d_ws + KK * sizeof(float));  // 2 MB packed emb

    const size_t need = (size_t)KK * 4 + (size_t)2 * EPLANE * 4;  // 2.01 MB

    hipLaunchKernelGGL(hn_kernel, dim3(KK / 32), dim3(256), 0, stream, emb, hn);
    if (ws_size >= need) {
        hipLaunchKernelGGL(pack_emb, dim3(EPLANE / 256), dim3(256), 0, stream,
                           emb, epk);
        hipLaunchKernelGGL((vq_fused<true>), dim3(NN / MT), dim3(1024), 0, stream,
                           x, emb, hn, epk, out);
    } else {
        hipLaunchKernelGGL((vq_fused<false>), dim3(NN / MT), dim3(1024), 0, stream,
                           x, emb, hn, epk, out);
    }
}

// Round 5
// 216.087 us; speedup vs baseline: 1.3658x; 1.0915x over previous
//
#include <hip/hip_runtime.h>

// VQ nearest-embedding, fused split-fp16 MFMA, double-buffered LDS.
// argmin_k ||x-e_k||^2 == argmin_k (0.5*||e_k||^2 - x.e_k).
// x = xh+xl, e = eh+el (fp16 RNE splits); 3 MFMA terms (hh, hl, lh).
// R9: one 1024-thread block/CU (16 waves, 4m x 4n), A split in-loop. 180us.
//     Diagnosis: ~3380 cyc/chunk invariant vs R6 -> wall is the per-chunk
//     drain+barrier + 96 scalar-dword VMEM instrs + 8-way LDS write conflicts.
// R10: amortize + widen (same 1-barrier dbuf template, param-level changes):
//   - chunk K-depth 16 -> 32 (LDA 24 -> 40): 64 barriers instead of 128.
//     LDS 120KB (1 block/CU as before).
//   - epk repacked quad-interleaved: B staging = 2 dwordx4 loads +
//     2 ds_write_b128 per thread (VMEM instrs halved, B-writes 4-way).
//   - accumulation order identical (same 128-step hh/hl/lh sequence)
//     -> bit-identical scores, absmax 0.

typedef __attribute__((ext_vector_type(8))) _Float16 half8v;  // 8 fp16 = 4 VGPRs
typedef __attribute__((ext_vector_type(16))) float floatx16;  // 32x32 acc
typedef unsigned int uint;
typedef unsigned short ushort;

#define DD 256
#define KK 2048
#define SS 1024
#define NN 32768
#define MT 128      // latents per block
#define NTT 256     // codes per kt tile (8 tiles cover K=2048)
#define CD 32       // chunk K-depth (halfs)
#define LDA 40      // LDS row stride in fp16 elems (80 B: 16B-aligned)
#define MFMA_F16 __builtin_amdgcn_mfma_f32_32x32x16_f16

union HU { _Float16 f; ushort u; };

__device__ __forceinline__ void split16(float v, ushort& h, ushort& l) {
    HU a, b;
    a.f = (_Float16)v;                       // RNE
    b.f = (_Float16)(v - (float)a.f);
    h = a.u; l = b.u;
}

__device__ __forceinline__ uint pk(ushort a, ushort b) {
    return (uint)a | ((uint)b << 16);
}

// 64 blocks: block b covers codes [b*32, b*32+32); 8 threads/code sum 32 d's.
__global__ __launch_bounds__(256) void hn_kernel(const float* __restrict__ emb,
                                                 float* __restrict__ hn) {
    __shared__ float red[256];
    const int tid = threadIdx.x;
    const int k = blockIdx.x * 32 + (tid & 31);
    const int j = tid >> 5;              // 0..7: d-chunk
    float a = 0.f;
#pragma unroll
    for (int i = 0; i < 32; ++i) {
        float e = emb[(size_t)(j * 32 + i) * KK + k];
        a += e * e;
    }
    red[tid] = a;
    __syncthreads();
    if (j == 0) {
        float s = a;
#pragma unroll
        for (int g = 1; g < 8; ++g) s += red[g * 32 + (tid & 31)];
        hn[k] = 0.5f * s;
    }
}

// emb (d,k) f32 -> epk quad-interleaved uint4 planes:
//   uint4 index (q*2 + p)*KK + k   holds, for plane p in {h,l}, code k,
//   packed d-pairs {4q..4q+3}  (element j = pack(d=8q+2j, d=8q+2j+1)).
__global__ __launch_bounds__(256) void pack_emb(const float* __restrict__ emb,
                                                uint4* __restrict__ epk) {
    int idx = blockIdx.x * 256 + threadIdx.x;     // 65536 = 32 quads * 2048 k
    int k = idx & (KK - 1);
    int q = idx >> 11;                            // d-quad: d = 8q..8q+7
    ushort h[8], l[8];
#pragma unroll
    for (int j = 0; j < 8; ++j) {
        float e = emb[(size_t)(8 * q + j) * KK + k];
        split16(e, h[j], l[j]);
    }
    uint4 H, L;
    H.x = pk(h[0], h[1]); H.y = pk(h[2], h[3]);
    H.z = pk(h[4], h[5]); H.w = pk(h[6], h[7]);
    L.x = pk(l[0], l[1]); L.y = pk(l[2], l[3]);
    L.z = pk(l[4], l[5]); L.w = pk(l[6], l[7]);
    epk[(size_t)(q * 2 + 0) * KK + k] = H;
    epk[(size_t)(q * 2 + 1) * KK + k] = L;
}

// PRE: B from quad-packed epk (dwordx4). !PRE: B from emb f32 + in-loop split.
template <bool PRE>
__global__ __launch_bounds__(1024, 4) void vq_fused(
        const float* __restrict__ x, const float* __restrict__ emb,
        const float* __restrict__ hn, const uint4* __restrict__ epk,
        float* __restrict__ out) {
    __shared__ ushort Ah[2][MT * LDA], Al[2][MT * LDA];     // 10 KB each plane/buf
    __shared__ ushort Bh[2][NTT * LDA], Bl[2][NTT * LDA];   // 20 KB each plane/buf
    __shared__ float sv[4][MT];
    __shared__ int   sc[4][MT];
    __shared__ int   bc[MT];

    const int tid = threadIdx.x;
    const int lane = tid & 63;
    const int wid = tid >> 6;          // 16 waves: 4(m) x 4(n)
    const int colk = lane & 31;
    const int half = lane >> 5;
    const int wm = (wid & 3) * 32;     // 4 m-tiles of 32 cover MT=128
    const int wn = (wid >> 2) * 64;    // 4 n-groups of 64 (2 tiles each)

    const int base_n = blockIdx.x * MT;
    const int bq = base_n >> 10;          // batch (SS = 1024)
    const int sb = base_n & (SS - 1);     // spatial base

    // staging assignment (1024 threads)
    // A: thread covers latent lat_a, d-pairs {d2a, d2a+8} of the 16-pair chunk.
    const int lat_a = tid & 127;
    const int d2a = tid >> 7;             // 0..7
    // B: thread covers code cod_b, plane p, pair-octet o (pairs o*8..o*8+7).
    const int cod_b = tid & 255;
    const int pB = (tid >> 8) & 1;        // 0=h, 1=l (uniform per wave)
    const int oB = tid >> 9;              // 0..1

    // A global base: d = 2*d2a + {0,1,16,17} + dt, latent sb+lat_a
    const float* xA = x + ((size_t)bq * DD + 2 * d2a) * SS + sb + lat_a;

    floatx16 acc[2];                      // 2 n-tiles (wn, wn+32)
#pragma unroll
    for (int j = 0; j < 2; ++j) acc[j] = (floatx16)(0.0f);

    float bestv[16];
    int bestc[16];
#pragma unroll
    for (int r = 0; r < 16; ++r) { bestv[r] = 3.4e38f; bestc[r] = 0; }

    float fa[4];
    uint4 ub0, ub1;        // PRE: 2 quads of this thread's plane
    float fb[16];          // !PRE raw f32

    // ---- prefetch chunk 0 (kt=0, dt=0) ----
    fa[0] = xA[0];
    fa[1] = xA[SS];
    fa[2] = xA[(size_t)16 * SS];
    fa[3] = xA[(size_t)17 * SS];
    if constexpr (PRE) {
        const int qg = 2 * oB;            // dt=0
        ub0 = epk[(size_t)(qg * 2 + pB) * KK + cod_b];
        ub1 = epk[(size_t)((qg + 1) * 2 + pB) * KK + cod_b];
    } else {
#pragma unroll
        for (int i = 0; i < 16; ++i)
            fb[i] = emb[(size_t)(oB * 16 + i) * KK + cod_b];
    }
    // ---- stage chunk 0 -> buffer 0 ----
    {
        ushort h0, l0, h1, l1, h2, l2, h3, l3;
        split16(fa[0], h0, l0); split16(fa[1], h1, l1);
        split16(fa[2], h2, l2); split16(fa[3], h3, l3);
        *reinterpret_cast<uint*>(&Ah[0][lat_a * LDA + 2 * d2a]) = pk(h0, h1);
        *reinterpret_cast<uint*>(&Al[0][lat_a * LDA + 2 * d2a]) = pk(l0, l1);
        *reinterpret_cast<uint*>(&Ah[0][lat_a * LDA + 2 * d2a + 16]) = pk(h2, h3);
        *reinterpret_cast<uint*>(&Al[0][lat_a * LDA + 2 * d2a + 16]) = pk(l2, l3);
        uint4 w0, w1;
        if constexpr (PRE) {
            w0 = ub0; w1 = ub1;
        } else {
            ushort h[16], l[16];
#pragma unroll
            for (int i = 0; i < 16; ++i) split16(fb[i], h[i], l[i]);
            const ushort* s = pB ? l : h;
            w0.x = pk(s[0], s[1]);  w0.y = pk(s[2], s[3]);
            w0.z = pk(s[4], s[5]);  w0.w = pk(s[6], s[7]);
            w1.x = pk(s[8], s[9]);  w1.y = pk(s[10], s[11]);
            w1.z = pk(s[12], s[13]); w1.w = pk(s[14], s[15]);
        }
        ushort* Bp = pB ? &Bl[0][0] : &Bh[0][0];
        *reinterpret_cast<uint4*>(&Bp[cod_b * LDA + oB * 16]) = w0;
        *reinterpret_cast<uint4*>(&Bp[cod_b * LDA + oB * 16 + 8]) = w1;
    }
    __syncthreads();

    for (int c = 0; c < 64; ++c) {           // 8 kt x 8 dt chunks of K-depth 32
        const int cur = c & 1, nxt = cur ^ 1;
        // ---- prefetch next chunk's globals (in flight during MFMA) ----
        if (c < 63) {
            const int c1 = c + 1;
            const int kt1 = c1 >> 3;
            const int dt1 = (c1 & 7) * CD;
            fa[0] = xA[(size_t)(dt1 + 0) * SS];
            fa[1] = xA[(size_t)(dt1 + 1) * SS];
            fa[2] = xA[(size_t)(dt1 + 16) * SS];
            fa[3] = xA[(size_t)(dt1 + 17) * SS];
            if constexpr (PRE) {
                const int qg = (dt1 >> 3) + 2 * oB;
                const size_t kb = (size_t)kt1 * NTT + cod_b;
                ub0 = epk[(size_t)(qg * 2 + pB) * KK + kb];
                ub1 = epk[(size_t)((qg + 1) * 2 + pB) * KK + kb];
            } else {
#pragma unroll
                for (int i = 0; i < 16; ++i)
                    fb[i] = emb[(size_t)(dt1 + oB * 16 + i) * KK
                                + kt1 * NTT + cod_b];
            }
        }
        // ---- fragments from current buffer + 2 k-substeps x 6 MFMA ----
        const int fo = colk * LDA + half * 8;
        {
            half8v ah = *reinterpret_cast<const half8v*>(&Ah[cur][fo + wm * LDA]);
            half8v al = *reinterpret_cast<const half8v*>(&Al[cur][fo + wm * LDA]);
            half8v bh0 = *reinterpret_cast<const half8v*>(&Bh[cur][fo + wn * LDA]);
            half8v bh1 = *reinterpret_cast<const half8v*>(&Bh[cur][fo + (wn + 32) * LDA]);
            half8v bl0 = *reinterpret_cast<const half8v*>(&Bl[cur][fo + wn * LDA]);
            half8v bl1 = *reinterpret_cast<const half8v*>(&Bl[cur][fo + (wn + 32) * LDA]);
            acc[0] = MFMA_F16(ah, bh0, acc[0], 0, 0, 0);
            acc[0] = MFMA_F16(ah, bl0, acc[0], 0, 0, 0);
            acc[0] = MFMA_F16(al, bh0, acc[0], 0, 0, 0);
            acc[1] = MFMA_F16(ah, bh1, acc[1], 0, 0, 0);
            acc[1] = MFMA_F16(ah, bl1, acc[1], 0, 0, 0);
            acc[1] = MFMA_F16(al, bh1, acc[1], 0, 0, 0);
        }
        {
            half8v ah = *reinterpret_cast<const half8v*>(&Ah[cur][fo + wm * LDA + 16]);
            half8v al = *reinterpret_cast<const half8v*>(&Al[cur][fo + wm * LDA + 16]);
            half8v bh0 = *reinterpret_cast<const half8v*>(&Bh[cur][fo + wn * LDA + 16]);
            half8v bh1 = *reinterpret_cast<const half8v*>(&Bh[cur][fo + (wn + 32) * LDA + 16]);
            half8v bl0 = *reinterpret_cast<const half8v*>(&Bl[cur][fo + wn * LDA + 16]);
            half8v bl1 = *reinterpret_cast<const half8v*>(&Bl[cur][fo + (wn + 32) * LDA + 16]);
            acc[0] = MFMA_F16(ah, bh0, acc[0], 0, 0, 0);
            acc[0] = MFMA_F16(ah, bl0, acc[0], 0, 0, 0);
            acc[0] = MFMA_F16(al, bh0, acc[0], 0, 0, 0);
            acc[1] = MFMA_F16(ah, bh1, acc[1], 0, 0, 0);
            acc[1] = MFMA_F16(ah, bl1, acc[1], 0, 0, 0);
            acc[1] = MFMA_F16(al, bh1, acc[1], 0, 0, 0);
        }

        // ---- stage prefetched -> NEXT buffer (overlaps MFMA) ----
        if (c < 63) {
            ushort h0, l0, h1, l1, h2, l2, h3, l3;
            split16(fa[0], h0, l0); split16(fa[1], h1, l1);
            split16(fa[2], h2, l2); split16(fa[3], h3, l3);
            *reinterpret_cast<uint*>(&Ah[nxt][lat_a * LDA + 2 * d2a]) = pk(h0, h1);
            *reinterpret_cast<uint*>(&Al[nxt][lat_a * LDA + 2 * d2a]) = pk(l0, l1);
            *reinterpret_cast<uint*>(&Ah[nxt][lat_a * LDA + 2 * d2a + 16]) = pk(h2, h3);
            *reinterpret_cast<uint*>(&Al[nxt][lat_a * LDA + 2 * d2a + 16]) = pk(l2, l3);
            uint4 w0, w1;
            if constexpr (PRE) {
                w0 = ub0; w1 = ub1;
            } else {
                ushort h[16], l[16];
#pragma unroll
                for (int i = 0; i < 16; ++i) split16(fb[i], h[i], l[i]);
                const ushort* s = pB ? l : h;
                w0.x = pk(s[0], s[1]);  w0.y = pk(s[2], s[3]);
                w0.z = pk(s[4], s[5]);  w0.w = pk(s[6], s[7]);
                w1.x = pk(s[8], s[9]);  w1.y = pk(s[10], s[11]);
                w1.z = pk(s[12], s[13]); w1.w = pk(s[14], s[15]);
            }
            ushort* Bp = pB ? &Bl[nxt][0] : &Bh[nxt][0];
            *reinterpret_cast<uint4*>(&Bp[cod_b * LDA + oB * 16]) = w0;
            *reinterpret_cast<uint4*>(&Bp[cod_b * LDA + oB * 16 + 8]) = w1;
        }
        // ---- per-kt epilogue: scores -> running per-lane argmin, reset acc ----
        if ((c & 7) == 7) {
            const int kt = c >> 3;
            const int cd0 = kt * NTT + wn + colk;
            const int cd1 = cd0 + 32;
            const float h0 = hn[cd0];
            const float h1 = hn[cd1];
#pragma unroll
            for (int r = 0; r < 16; ++r) {
                float s0 = h0 - acc[0][r];
                float s1 = h1 - acc[1][r];
                float v = s0; int cd = cd0;
                if (s1 < s0) { v = s1; cd = cd1; }   // strict <: smaller code wins ties
                if (v < bestv[r]) { bestv[r] = v; bestc[r] = cd; }
                acc[0][r] = 0.f;
                acc[1][r] = 0.f;
            }
        }
        __syncthreads();   // single barrier per chunk (dbuf)
    }

    // ---- cross-lane argmin: butterfly over the 32 colk lanes ----
#pragma unroll
    for (int r = 0; r < 16; ++r) {
        float v = bestv[r];
        int cd = bestc[r];
#pragma unroll
        for (int mk = 1; mk < 32; mk <<= 1) {
            float ov = __shfl_xor(v, mk);
            int oc = __shfl_xor(cd, mk);
            if (ov < v || (ov == v && oc < cd)) { v = ov; cd = oc; }
        }
        if (colk == 0) {
            const int row = (r & 3) + 8 * (r >> 2) + 4 * half;  // verified C/D map
            sv[wid >> 2][wm + row] = v;
            sc[wid >> 2][wm + row] = cd;
        }
    }
    __syncthreads();
    // ---- combine the 4 n-wave groups ----
    if (tid < MT) {
        float v = sv[0][tid]; int cd = sc[0][tid];
#pragma unroll
        for (int g = 1; g < 4; ++g) {
            float ov = sv[g][tid]; int oc = sc[g][tid];
            if (ov < v || (ov == v && oc < cd)) { v = ov; cd = oc; }
        }
        bc[tid] = cd;
    }
    __syncthreads();
    // ---- fused gather: out[(bq*DD+d)*SS + sb + m] = emb[d*KK + bc[m]] ----
    {
        const int mq = tid & 31;     // float4 group along m (128 cols = 32 groups)
        const int dg = tid >> 5;     // 0..31, 8 d's each
        const int k0 = bc[mq * 4 + 0];
        const int k1 = bc[mq * 4 + 1];
        const int k2 = bc[mq * 4 + 2];
        const int k3 = bc[mq * 4 + 3];
#pragma unroll 4
        for (int dd = 0; dd < 8; ++dd) {
            const int d = dg * 8 + dd;
            const float* er = emb + (size_t)d * KK;
            float4 o = make_float4(er[k0], er[k1], er[k2], er[k3]);
            reinterpret_cast<float4*>(&out[((size_t)bq * DD + d) * SS + sb])[mq] = o;
        }
    }
}

extern "C" void kernel_launch(void* const* d_in, const int* in_sizes, int n_in,
                              void* d_out, int out_size, void* d_ws, size_t ws_size,
                              hipStream_t stream) {
    const float* x = (const float*)d_in[0];     // (32,256,32,32)
    const float* emb = (const float*)d_in[1];   // (256,2048)
    float* out = (float*)d_out;
    float* hn = (float*)d_ws;                   // 2048 f32 = 8 KB (proven safe)
    uint4* epk = (uint4*)((char*)d_ws + KK * sizeof(float));  // 2 MB packed emb

    // 32 quads * 2 planes * 2048 codes * 16 B = 2 MB
    const size_t need = (size_t)KK * 4 + (size_t)32 * 2 * KK * 16;

    hipLaunchKernelGGL(hn_kernel, dim3(KK / 32), dim3(256), 0, stream, emb, hn);
    if (ws_size >= need) {
        hipLaunchKernelGGL(pack_emb, dim3(65536 / 256), dim3(256), 0, stream,
                           emb, epk);
        hipLaunchKernelGGL((vq_fused<true>), dim3(NN / MT), dim3(1024), 0, stream,
                           x, emb, hn, epk, out);
    } else {
        hipLaunchKernelGGL((vq_fused<false>), dim3(NN / MT), dim3(1024), 0, stream,
                           x, emb, hn, epk, out);
    }
}